// Round 7
// baseline (1036.239 us; speedup 1.0000x reference)
//
#include <hip/hip_runtime.h>
#include <hip/hip_fp16.h>

#define N_NODES 50000
#define N_EDGES 800000
#define IN_C 128
#define HID 32
#define HC 128
#define OUT_C 16
#define NGRAPH 64
#define PNB 125  // nodes per block in pool
#define TPB 4    // targets per block in edge attn

typedef __attribute__((ext_vector_type(8))) _Float16 half8;
typedef __attribute__((ext_vector_type(4))) _Float16 half4v;
typedef __attribute__((ext_vector_type(4))) float floatx4;

// ---------------- CSR build ----------------
__global__ void k_hist(const int* __restrict__ tgt, int* __restrict__ deg) {
  int i = blockIdx.x * blockDim.x + threadIdx.x;
  if (i < N_EDGES) atomicAdd(&deg[tgt[i]], 1);
}

__global__ __launch_bounds__(1024) void k_scan(const int* __restrict__ deg,
                                               int* __restrict__ offs,
                                               int* __restrict__ cursor) {
  __shared__ int wsum[16];
  __shared__ int carry_s;
  int lane = threadIdx.x & 63, wid = threadIdx.x >> 6;
  if (threadIdx.x == 0) { carry_s = 0; offs[0] = 0; }
  __syncthreads();
  for (int base = 0; base < N_NODES; base += 1024) {
    int i = base + threadIdx.x;
    int v = (i < N_NODES) ? deg[i] : 0;
    int x = v;
#pragma unroll
    for (int off = 1; off < 64; off <<= 1) {
      int t = __shfl_up(x, off, 64);
      if (lane >= off) x += t;
    }
    if (lane == 63) wsum[wid] = x;
    __syncthreads();
    if (wid == 0 && lane < 16) {
      int s = wsum[lane];
#pragma unroll
      for (int off = 1; off < 16; off <<= 1) {
        int t = __shfl_up(s, off, 64);
        if (lane >= off) s += t;
      }
      wsum[lane] = s;
    }
    __syncthreads();
    int add = (wid > 0 ? wsum[wid - 1] : 0) + carry_s;
    int incl = x + add;
    if (i < N_NODES) { offs[i + 1] = incl; cursor[i] = incl - v; }
    __syncthreads();
    if (threadIdx.x == 1023) carry_s = incl;
    __syncthreads();
  }
}

__global__ void k_scatter(const int* __restrict__ src, const int* __restrict__ tgt,
                          int* __restrict__ cursor, int* __restrict__ srcs,
                          int* __restrict__ eids) {
  int i = blockIdx.x * blockDim.x + threadIdx.x;
  if (i < N_EDGES) {
    int pos = atomicAdd(&cursor[tgt[i]], 1);
    srcs[pos] = src[i];
    eids[pos] = i;
  }
}

// ---------------- conversions ----------------
// fp32 -> fp16 hi/lo split (hi + lo recovers ~22 mantissa bits)
__global__ void k_conv_x(const float* __restrict__ x, _Float16* __restrict__ hi,
                         _Float16* __restrict__ lo) {
  int i = blockIdx.x * 256 + threadIdx.x;
  if (i < N_NODES * HC) {
    float v = x[i];
    _Float16 h = (_Float16)v;
    hi[i] = h;
    lo[i] = (_Float16)(v - (float)h);
  }
}

// W^T packed [512 cols][128 k] fp16 hi/lo. One block per output col.
__global__ __launch_bounds__(128) void k_conv_w(
    const float* __restrict__ wq, const float* __restrict__ wk,
    const float* __restrict__ wv, const float* __restrict__ ws,
    _Float16* __restrict__ wthi, _Float16* __restrict__ wtlo) {
  int g = blockIdx.x;          // 0..511 global output col
  int k = threadIdx.x;         // 0..127
  const float* w = (g < 128) ? wq : (g < 256) ? wk : (g < 384) ? wv : ws;
  int c = g & 127;
  float v = w[k * HC + c];
  _Float16 h = (_Float16)v;
  wthi[g * HC + k] = h;
  wtlo[g * HC + k] = (_Float16)(v - (float)h);
}

// we transposed: wet[g][j] = we[j][g]  (coalesced reads in p-phase)
__global__ void k_conv_we(const float* __restrict__ we1, const float* __restrict__ we2,
                          float* __restrict__ wet1, float* __restrict__ wet2) {
  int i = blockIdx.x * 256 + threadIdx.x;
  if (i >= 2 * HID * HC) return;
  const float* we = (i < HID * HC) ? we1 : we2;
  float* wet = (i < HID * HC) ? wet1 : wet2;
  int idx = i & (HID * HC - 1);
  int g = idx >> 5, j = idx & 31;
  wet[g * 32 + j] = we[j * HC + g];
}

// ---------------- MFMA node GEMM ----------------
// Block: 32 rows x 512 cols, 4 waves; wave w computes matrix w (q/k/v/skip).
// hi/lo fp16 split on A and B -> ~fp32 accuracy with 3 MFMAs per tile-k.
// Epilogue folds bias, fp16 store of k/v, and p = per-head q @ we^T via LDS.
__global__ __launch_bounds__(256) void k_gemm(
    const _Float16* __restrict__ ahi, const _Float16* __restrict__ alo,
    const _Float16* __restrict__ wthi, const _Float16* __restrict__ wtlo,
    const float* __restrict__ bq, const float* __restrict__ bk,
    const float* __restrict__ bv, const float* __restrict__ bs,
    const float* __restrict__ wet,
    float* __restrict__ qn, __half* __restrict__ kn16, __half* __restrict__ vn16,
    float* __restrict__ sk, float* __restrict__ p) {
  int wv = threadIdx.x >> 6;
  int lane = threadIdx.x & 63;
  int quad = lane >> 4, l16 = lane & 15;
  int r0 = blockIdx.x * 32;
  half8 Ahi[2][4], Alo[2][4];
#pragma unroll
  for (int rt = 0; rt < 2; ++rt)
#pragma unroll
    for (int kc = 0; kc < 4; ++kc) {
      int row = min(r0 + rt * 16 + l16, N_NODES - 1);
      size_t off = (size_t)row * HC + kc * 32 + quad * 8;
      Ahi[rt][kc] = *(const half8*)&ahi[off];
      Alo[rt][kc] = *(const half8*)&alo[off];
    }
  floatx4 acc[2][8];
#pragma unroll
  for (int rt = 0; rt < 2; ++rt)
#pragma unroll
    for (int ct = 0; ct < 8; ++ct) acc[rt][ct] = (floatx4){0.f, 0.f, 0.f, 0.f};
#pragma unroll
  for (int ct = 0; ct < 8; ++ct) {
    int col = (wv << 7) + (ct << 4) + l16;
    half8 Bhi[4], Blo[4];
#pragma unroll
    for (int kc = 0; kc < 4; ++kc) {
      size_t off = (size_t)col * HC + kc * 32 + quad * 8;
      Bhi[kc] = *(const half8*)&wthi[off];
      Blo[kc] = *(const half8*)&wtlo[off];
    }
#pragma unroll
    for (int rt = 0; rt < 2; ++rt)
#pragma unroll
      for (int kc = 0; kc < 4; ++kc) {
        acc[rt][ct] = __builtin_amdgcn_mfma_f32_16x16x32_f16(Ahi[rt][kc], Bhi[kc], acc[rt][ct], 0, 0, 0);
        acc[rt][ct] = __builtin_amdgcn_mfma_f32_16x16x32_f16(Ahi[rt][kc], Blo[kc], acc[rt][ct], 0, 0, 0);
        acc[rt][ct] = __builtin_amdgcn_mfma_f32_16x16x32_f16(Alo[rt][kc], Bhi[kc], acc[rt][ct], 0, 0, 0);
      }
  }
  __shared__ float qsh[32][HC];
  const float* bias = (wv == 0) ? bq : (wv == 1) ? bk : (wv == 2) ? bv : bs;
#pragma unroll
  for (int ct = 0; ct < 8; ++ct) {
    int c = (ct << 4) + l16;
    float b = bias[c];
#pragma unroll
    for (int rt = 0; rt < 2; ++rt)
#pragma unroll
      for (int reg = 0; reg < 4; ++reg) {
        int rl = rt * 16 + quad * 4 + reg;    // C/D: col=lane&15, row=quad*4+reg
        int row = r0 + rl;
        float val = acc[rt][ct][reg] + b;
        if (wv == 0) qsh[rl][c] = val;
        if (row < N_NODES) {
          size_t o = (size_t)row * HC + c;
          if (wv == 0) qn[o] = val;
          else if (wv == 1) kn16[o] = __float2half(val);
          else if (wv == 2) vn16[o] = __float2half(val);
          else sk[o] = val;
        }
      }
  }
  __syncthreads();
  // p[row][c=h*32+j] = sum_d qsh[row][h*32+d] * we[j][h*32+d]  (wet[(h*32+d)*32+j])
  int c = threadIdx.x & 127;
  int hseg = threadIdx.x >> 7;
  int hb = (c >> 5) << 5, j = c & 31;
  float pa[16];
#pragma unroll
  for (int i = 0; i < 16; ++i) pa[i] = 0.f;
  for (int d = 0; d < 32; ++d) {
    float wev = wet[(hb + d) * 32 + j];
#pragma unroll
    for (int i = 0; i < 16; ++i) pa[i] = fmaf(qsh[hseg * 16 + i][hb + d], wev, pa[i]);
  }
#pragma unroll
  for (int i = 0; i < 16; ++i) {
    int row = r0 + hseg * 16 + i;
    if (row < N_NODES) p[(size_t)row * HC + c] = pa[i];
  }
}

// ---------------- edge attention ----------------
// 2 edges/iter, 32 lanes/edge, float4 features; fp16 k/v gather. Writes h fp32 +
// h16 hi/lo (fp16 split) so the next layer's MFMA GEMM consumes it directly.
__global__ __launch_bounds__(256) void k_edge_attn(
    const int* __restrict__ offs, const int* __restrict__ srcs,
    const int* __restrict__ eids, const float* __restrict__ ea,
    const float* __restrict__ qn, const __half* __restrict__ kn16,
    const __half* __restrict__ vn16, const float* __restrict__ sk,
    const float* __restrict__ p, const float* __restrict__ we,
    float* __restrict__ out, _Float16* __restrict__ o16hi,
    _Float16* __restrict__ o16lo) {
  int lane = threadIdx.x & 63;
  int wv_ = threadIdx.x >> 6;
  int t = blockIdx.x * TPB + wv_;
  int l32 = lane & 31;
  int half_ = lane >> 5;
  int f = 4 * l32;
  int g = l32 & 7;
  int ed = 4 * g;
  int h = l32 >> 3;
  int e0 = offs[t], e1 = offs[t + 1];
  float4 q4 = *(const float4*)&qn[t * HC + f];
  float4 p4 = *(const float4*)&p[t * HC + f];
  const float inv_sqrt = 0.17677669529663687f;
  float m = -1e30f, den = 0.f;
  float4 acc = {0.f, 0.f, 0.f, 0.f}, tac = {0.f, 0.f, 0.f, 0.f};
  for (int base = e0; base < e1; base += 64) {
    int cnt = min(64, e1 - base);
    int li = base + lane;
    int sl = (li < e1) ? srcs[li] : 0;
    int el = (li < e1) ? eids[li] : 0;
    for (int jj = 0; jj < cnt; jj += 2) {
      int j = jj + half_;
      bool val = (j < cnt);
      int jc = min(j, cnt - 1);
      int s = __shfl(sl, jc, 64);
      int eid = __shfl(el, jc, 64);
      const __half2* kp = (const __half2*)&kn16[s * HC + f];
      const __half2* vp = (const __half2*)&vn16[s * HC + f];
      __half2 kh0 = kp[0], kh1 = kp[1];
      __half2 vh0 = vp[0], vh1 = vp[1];
      float4 e4 = *(const float4*)&ea[eid * HID + ed];
      float2 k01 = __half22float2(kh0), k23 = __half22float2(kh1);
      float2 v01 = __half22float2(vh0), v23 = __half22float2(vh1);
      float part = fmaf(q4.x, k01.x, fmaf(q4.y, k01.y,
                   fmaf(q4.z, k23.x, fmaf(q4.w, k23.y,
                   fmaf(p4.x, e4.x, fmaf(p4.y, e4.y,
                   fmaf(p4.z, e4.z, p4.w * e4.w)))))));
      part += __shfl_xor(part, 1, 64);
      part += __shfl_xor(part, 2, 64);
      part += __shfl_xor(part, 4, 64);
      float a = part * inv_sqrt;
      float nm = fmaxf(m, a);
      float sc = __expf(m - nm);
      float w = val ? __expf(a - nm) : 0.f;
      m = nm;
      den = fmaf(den, sc, w);
      acc.x = fmaf(acc.x, sc, w * v01.x);
      acc.y = fmaf(acc.y, sc, w * v01.y);
      acc.z = fmaf(acc.z, sc, w * v23.x);
      acc.w = fmaf(acc.w, sc, w * v23.y);
      tac.x = fmaf(tac.x, sc, w * e4.x);
      tac.y = fmaf(tac.y, sc, w * e4.y);
      tac.z = fmaf(tac.z, sc, w * e4.z);
      tac.w = fmaf(tac.w, sc, w * e4.w);
    }
  }
  float m_o = __shfl_xor(m, 32, 64);
  float M = fmaxf(m, m_o);
  float s_s = __expf(m - M), s_o = __expf(m_o - M);
  float den_o = __shfl_xor(den, 32, 64);
  float dtot = fmaf(den, s_s, den_o * s_o);
  float4 A, T;
  A.x = fmaf(acc.x, s_s, __shfl_xor(acc.x, 32, 64) * s_o);
  A.y = fmaf(acc.y, s_s, __shfl_xor(acc.y, 32, 64) * s_o);
  A.z = fmaf(acc.z, s_s, __shfl_xor(acc.z, 32, 64) * s_o);
  A.w = fmaf(acc.w, s_s, __shfl_xor(acc.w, 32, 64) * s_o);
  T.x = fmaf(tac.x, s_s, __shfl_xor(tac.x, 32, 64) * s_o);
  T.y = fmaf(tac.y, s_s, __shfl_xor(tac.y, 32, 64) * s_o);
  T.z = fmaf(tac.z, s_s, __shfl_xor(tac.z, 32, 64) * s_o);
  T.w = fmaf(tac.w, s_s, __shfl_xor(tac.w, 32, 64) * s_o);
  __shared__ float tl[TPB][4 * 33];
  if (half_ == 0) *(float4*)&tl[wv_][h * 33 + ed] = T;
  float4 fx = {0.f, 0.f, 0.f, 0.f};
  for (int j = 0; j < 32; ++j) {
    float tv = tl[wv_][h * 33 + j];
    float4 w4 = *(const float4*)&we[j * HC + f];
    fx.x = fmaf(tv, w4.x, fx.x);
    fx.y = fmaf(tv, w4.y, fx.y);
    fx.z = fmaf(tv, w4.z, fx.z);
    fx.w = fmaf(tv, w4.w, fx.w);
  }
  float4 sk4 = *(const float4*)&sk[t * HC + f];
  float4 o;
  float rd = (e1 > e0) ? (1.0f / dtot) : 0.f;
  o.x = (A.x + fx.x) * rd + sk4.x;
  o.y = (A.y + fx.y) * rd + sk4.y;
  o.z = (A.z + fx.z) * rd + sk4.z;
  o.w = (A.w + fx.w) * rd + sk4.w;
  o.x = o.x > 0.f ? o.x : __expf(o.x) - 1.f;
  o.y = o.y > 0.f ? o.y : __expf(o.y) - 1.f;
  o.z = o.z > 0.f ? o.z : __expf(o.z) - 1.f;
  o.w = o.w > 0.f ? o.w : __expf(o.w) - 1.f;
  if (half_ == 0) {
    *(float4*)&out[t * HC + f] = o;
    half4v vhi = {(_Float16)o.x, (_Float16)o.y, (_Float16)o.z, (_Float16)o.w};
    half4v vlo = {(_Float16)(o.x - (float)vhi.x), (_Float16)(o.y - (float)vhi.y),
                  (_Float16)(o.z - (float)vhi.z), (_Float16)(o.w - (float)vhi.w)};
    *(half4v*)&o16hi[t * HC + f] = vhi;
    *(half4v*)&o16lo[t * HC + f] = vlo;
  }
}

// ---------------- global mean pool ----------------
__global__ __launch_bounds__(128) void k_pool_sum(const float* __restrict__ h,
                                                  const int* __restrict__ batch,
                                                  float* __restrict__ psum) {
  int c = threadIdx.x;
  int n0 = blockIdx.x * PNB;
  int n1 = n0 + PNB;
  float acc = 0.f;
  int curb = batch[n0];
  for (int n = n0; n < n1; ++n) {
    int b = batch[n];
    if (b != curb) {
      atomicAdd(&psum[curb * HC + c], acc);
      acc = 0.f;
      curb = b;
    }
    acc += h[n * HC + c];
  }
  atomicAdd(&psum[curb * HC + c], acc);
}

// ---------------- classifier + log_softmax ----------------
__global__ __launch_bounds__(1024) void k_classify(const float* __restrict__ psum,
                                                   const int* __restrict__ batch,
                                                   const float* __restrict__ wlin,
                                                   const float* __restrict__ blin,
                                                   float* __restrict__ out) {
  int tid = threadIdx.x;
  int b = tid >> 4, o = tid & 15;
  int lo = 0, hi = N_NODES;
  while (lo < hi) { int mid = (lo + hi) >> 1; if (batch[mid] < b) lo = mid + 1; else hi = mid; }
  int start = lo;
  lo = 0; hi = N_NODES;
  while (lo < hi) { int mid = (lo + hi) >> 1; if (batch[mid] <= b) lo = mid + 1; else hi = mid; }
  float cnt = fmaxf((float)(lo - start), 1.0f);
  float dot = 0.f;
  for (int d = 0; d < HC; ++d) dot = fmaf(psum[b * HC + d], wlin[d * OUT_C + o], dot);
  float acc = dot / cnt + blin[o];
  float mx = acc;
#pragma unroll
  for (int off = 8; off > 0; off >>= 1) mx = fmaxf(mx, __shfl_xor(mx, off, 64));
  float ex = __expf(acc - mx);
  float sum = ex;
#pragma unroll
  for (int off = 8; off > 0; off >>= 1) sum += __shfl_xor(sum, off, 64);
  out[tid] = acc - mx - logf(sum);
}

extern "C" void kernel_launch(void* const* d_in, const int* in_sizes, int n_in,
                              void* d_out, int out_size, void* d_ws, size_t ws_size,
                              hipStream_t stream) {
  const float* x = (const float*)d_in[0];
  const int* ei = (const int*)d_in[1];
  const float* ea = (const float*)d_in[2];
  const int* batch = (const int*)d_in[3];
  const float* wq1 = (const float*)d_in[4];  const float* bq1 = (const float*)d_in[5];
  const float* wk1 = (const float*)d_in[6];  const float* bk1 = (const float*)d_in[7];
  const float* wv1 = (const float*)d_in[8];  const float* bv1 = (const float*)d_in[9];
  const float* we1 = (const float*)d_in[10];
  const float* ws1 = (const float*)d_in[11]; const float* bs1 = (const float*)d_in[12];
  const float* wq2 = (const float*)d_in[13]; const float* bq2 = (const float*)d_in[14];
  const float* wk2 = (const float*)d_in[15]; const float* bk2 = (const float*)d_in[16];
  const float* wv2 = (const float*)d_in[17]; const float* bv2 = (const float*)d_in[18];
  const float* we2 = (const float*)d_in[19];
  const float* ws2 = (const float*)d_in[20]; const float* bs2 = (const float*)d_in[21];
  const float* wlin = (const float*)d_in[22]; const float* blin = (const float*)d_in[23];

  const int* srcI = ei;
  const int* tgtI = ei + N_EDGES;

  char* wsb = (char*)d_ws;
  size_t off = 0;
  auto alloc = [&](size_t bytes) -> void* {
    void* ptr = wsb + off;
    off += (bytes + 255) & ~(size_t)255;
    return ptr;
  };
  float* qn = (float*)alloc((size_t)N_NODES * HC * 4);
  __half* kn16 = (__half*)alloc((size_t)N_NODES * HC * 2);
  __half* vn16 = (__half*)alloc((size_t)N_NODES * HC * 2);
  float* sk = (float*)alloc((size_t)N_NODES * HC * 4);
  float* p  = (float*)alloc((size_t)N_NODES * HC * 4);
  float* h  = (float*)alloc((size_t)N_NODES * HC * 4);
  _Float16* in16hi = (_Float16*)alloc((size_t)N_NODES * HC * 2);  // x16, then h16 (layer2 in)
  _Float16* in16lo = (_Float16*)alloc((size_t)N_NODES * HC * 2);
  _Float16* wt1hi = (_Float16*)alloc((size_t)512 * HC * 2);
  _Float16* wt1lo = (_Float16*)alloc((size_t)512 * HC * 2);
  _Float16* wt2hi = (_Float16*)alloc((size_t)512 * HC * 2);
  _Float16* wt2lo = (_Float16*)alloc((size_t)512 * HC * 2);
  float* wet1 = (float*)alloc((size_t)HID * HC * 4);
  float* wet2 = (float*)alloc((size_t)HID * HC * 4);
  float* psum = (float*)alloc((size_t)NGRAPH * HC * 4);
  int* deg    = (int*)alloc((size_t)N_NODES * 4);
  int* offs   = (int*)alloc((size_t)(N_NODES + 1) * 4);
  int* cursor = (int*)alloc((size_t)N_NODES * 4);
  int* srcs   = (int*)alloc((size_t)N_EDGES * 4);
  int* eids   = (int*)alloc((size_t)N_EDGES * 4);

  // CSR build
  hipMemsetAsync(deg, 0, (size_t)N_NODES * 4, stream);
  k_hist<<<(N_EDGES + 255) / 256, 256, 0, stream>>>(tgtI, deg);
  k_scan<<<1, 1024, 0, stream>>>(deg, offs, cursor);
  k_scatter<<<(N_EDGES + 255) / 256, 256, 0, stream>>>(srcI, tgtI, cursor, srcs, eids);

  // Precision-split conversions
  k_conv_x<<<(N_NODES * HC + 255) / 256, 256, 0, stream>>>(x, in16hi, in16lo);
  k_conv_w<<<512, 128, 0, stream>>>(wq1, wk1, wv1, ws1, wt1hi, wt1lo);
  k_conv_w<<<512, 128, 0, stream>>>(wq2, wk2, wv2, ws2, wt2hi, wt2lo);
  k_conv_we<<<32, 256, 0, stream>>>(we1, we2, wet1, wet2);

  int gemm_grid = (N_NODES + 31) / 32;
  // Layer 1
  k_gemm<<<gemm_grid, 256, 0, stream>>>(in16hi, in16lo, wt1hi, wt1lo,
                                        bq1, bk1, bv1, bs1, wet1,
                                        qn, kn16, vn16, sk, p);
  k_edge_attn<<<N_NODES / TPB, 64 * TPB, 0, stream>>>(offs, srcs, eids, ea, qn, kn16,
                                                      vn16, sk, p, we1, h, in16hi, in16lo);
  // Layer 2
  k_gemm<<<gemm_grid, 256, 0, stream>>>(in16hi, in16lo, wt2hi, wt2lo,
                                        bq2, bk2, bv2, bs2, wet2,
                                        qn, kn16, vn16, sk, p);
  k_edge_attn<<<N_NODES / TPB, 64 * TPB, 0, stream>>>(offs, srcs, eids, ea, qn, kn16,
                                                      vn16, sk, p, we2, h, in16hi, in16lo);

  // Pool + classify
  hipMemsetAsync(psum, 0, (size_t)NGRAPH * HC * 4, stream);
  k_pool_sum<<<N_NODES / PNB, 128, 0, stream>>>(h, batch, psum);
  k_classify<<<1, 1024, 0, stream>>>(psum, batch, wlin, blin, (float*)d_out);
}

// Round 8
// 815.205 us; speedup vs baseline: 1.2711x; 1.2711x over previous
//
#include <hip/hip_runtime.h>
#include <hip/hip_fp16.h>

#define N_NODES 50000
#define N_EDGES 800000
#define IN_C 128
#define HID 32
#define HC 128
#define OUT_C 16
#define NGRAPH 64
#define PNB 125  // nodes per block in pool
#define TPB 4    // targets per block in edge attn

typedef __attribute__((ext_vector_type(8))) _Float16 half8;
typedef __attribute__((ext_vector_type(4))) _Float16 half4v;
typedef __attribute__((ext_vector_type(4))) float floatx4;

// ---------------- CSR build ----------------
__global__ void k_hist(const int* __restrict__ tgt, int* __restrict__ deg) {
  int i = blockIdx.x * blockDim.x + threadIdx.x;
  if (i < N_EDGES) atomicAdd(&deg[tgt[i]], 1);
}

__global__ __launch_bounds__(1024) void k_scan(const int* __restrict__ deg,
                                               int* __restrict__ offs,
                                               int* __restrict__ cursor) {
  __shared__ int wsum[16];
  __shared__ int carry_s;
  int lane = threadIdx.x & 63, wid = threadIdx.x >> 6;
  if (threadIdx.x == 0) { carry_s = 0; offs[0] = 0; }
  __syncthreads();
  for (int base = 0; base < N_NODES; base += 1024) {
    int i = base + threadIdx.x;
    int v = (i < N_NODES) ? deg[i] : 0;
    int x = v;
#pragma unroll
    for (int off = 1; off < 64; off <<= 1) {
      int t = __shfl_up(x, off, 64);
      if (lane >= off) x += t;
    }
    if (lane == 63) wsum[wid] = x;
    __syncthreads();
    if (wid == 0 && lane < 16) {
      int s = wsum[lane];
#pragma unroll
      for (int off = 1; off < 16; off <<= 1) {
        int t = __shfl_up(s, off, 64);
        if (lane >= off) s += t;
      }
      wsum[lane] = s;
    }
    __syncthreads();
    int add = (wid > 0 ? wsum[wid - 1] : 0) + carry_s;
    int incl = x + add;
    if (i < N_NODES) { offs[i + 1] = incl; cursor[i] = incl - v; }
    __syncthreads();
    if (threadIdx.x == 1023) carry_s = incl;
    __syncthreads();
  }
}

__global__ void k_scatter(const int* __restrict__ src, const int* __restrict__ tgt,
                          int* __restrict__ cursor, int* __restrict__ srcs,
                          int* __restrict__ eids) {
  int i = blockIdx.x * blockDim.x + threadIdx.x;
  if (i < N_EDGES) {
    int pos = atomicAdd(&cursor[tgt[i]], 1);
    srcs[pos] = src[i];
    eids[pos] = i;
  }
}

// ---------------- conversions ----------------
__global__ void k_conv_x(const float* __restrict__ x, _Float16* __restrict__ x16) {
  int i = blockIdx.x * 256 + threadIdx.x;
  if (i < N_NODES * HC) x16[i] = (_Float16)x[i];
}

// W^T packed [512 cols][128 k] fp16. One block per output col.
__global__ __launch_bounds__(128) void k_conv_w(
    const float* __restrict__ wq, const float* __restrict__ wk,
    const float* __restrict__ wv, const float* __restrict__ ws,
    _Float16* __restrict__ wt) {
  int g = blockIdx.x;          // 0..511 global output col
  int k = threadIdx.x;         // 0..127
  const float* w = (g < 128) ? wq : (g < 256) ? wk : (g < 384) ? wv : ws;
  int c = g & 127;
  wt[g * HC + k] = (_Float16)w[k * HC + c];
}

// ---------------- MFMA node GEMM ----------------
// Grid (782 row-tiles, 4 matrices). Block = 4 waves; wave owns 16 rows x 128 cols.
// Pure fp16 inputs, fp32 accumulate. No LDS, no barriers, block-uniform output.
__global__ __launch_bounds__(256) void k_gemm(
    const _Float16* __restrict__ ain,   // [N][128] fp16
    const _Float16* __restrict__ wt,    // [512][128] fp16 = W^T
    const float* __restrict__ bq, const float* __restrict__ bk,
    const float* __restrict__ bv, const float* __restrict__ bs,
    __half* __restrict__ qn16, __half* __restrict__ kn16,
    __half* __restrict__ vn16, float* __restrict__ sk) {
  int wv = threadIdx.x >> 6, lane = threadIdx.x & 63;
  int quad = lane >> 4, l16 = lane & 15;
  int r0 = blockIdx.x * 64 + wv * 16;
  int cb = blockIdx.y;                  // 0=q 1=k 2=v 3=skip
  half8 A[4];
  int arow = min(r0 + l16, N_NODES - 1);
#pragma unroll
  for (int kc = 0; kc < 4; ++kc)
    A[kc] = *(const half8*)&ain[(size_t)arow * HC + kc * 32 + quad * 8];
  floatx4 acc[8];
#pragma unroll
  for (int ct = 0; ct < 8; ++ct) acc[ct] = (floatx4){0.f, 0.f, 0.f, 0.f};
#pragma unroll
  for (int ct = 0; ct < 8; ++ct) {
    int col = (cb << 7) + (ct << 4) + l16;
#pragma unroll
    for (int kc = 0; kc < 4; ++kc) {
      half8 B = *(const half8*)&wt[(size_t)col * HC + kc * 32 + quad * 8];
      acc[ct] = __builtin_amdgcn_mfma_f32_16x16x32_f16(A[kc], B, acc[ct], 0, 0, 0);
    }
  }
  const float* bias = (cb == 0) ? bq : (cb == 1) ? bk : (cb == 2) ? bv : bs;
#pragma unroll
  for (int ct = 0; ct < 8; ++ct) {
    int lc = (ct << 4) + l16;
    float b = bias[lc];
#pragma unroll
    for (int reg = 0; reg < 4; ++reg) {
      int row = r0 + quad * 4 + reg;     // C/D: col=lane&15, row=quad*4+reg
      if (row < N_NODES) {
        float val = acc[ct][reg] + b;
        size_t o = (size_t)row * HC + lc;
        if (cb == 0) qn16[o] = __float2half(val);
        else if (cb == 1) kn16[o] = __float2half(val);
        else if (cb == 2) vn16[o] = __float2half(val);
        else sk[o] = val;
      }
    }
  }
}

// ---------------- p = per-head q @ we^T (VALU; round-5 verified pattern) ------
// p[n][h*32+j] = sum_d q[n][h*32+d] * we[j][h*32+d]
__global__ __launch_bounds__(128) void k_pcomp(const __half* __restrict__ qn16,
                                               const float* __restrict__ we,
                                               float* __restrict__ p) {
  int c = threadIdx.x;
  int n0 = blockIdx.x * 16;
  __shared__ float qs[16][HC];
#pragma unroll
  for (int i = 0; i < 16; ++i)
    qs[i][c] = __half2float(qn16[(size_t)(n0 + i) * HC + c]);
  __syncthreads();
  int hb = (c >> 5) << 5, j = c & 31;
  float a[16];
#pragma unroll
  for (int i = 0; i < 16; ++i) a[i] = 0.f;
  for (int d = 0; d < 32; ++d) {
    float wev = we[j * HC + hb + d];
#pragma unroll
    for (int i = 0; i < 16; ++i) a[i] = fmaf(qs[i][hb + d], wev, a[i]);
  }
#pragma unroll
  for (int i = 0; i < 16; ++i) p[(size_t)(n0 + i) * HC + c] = a[i];
}

// ---------------- edge attention ----------------
// 2 edges/iter, 32 lanes/edge, float4 features; fp16 q/k/v. Writes h fp32 (pool)
// + h fp16 (next layer's GEMM input).
__global__ __launch_bounds__(256) void k_edge_attn(
    const int* __restrict__ offs, const int* __restrict__ srcs,
    const int* __restrict__ eids, const float* __restrict__ ea,
    const __half* __restrict__ qn16, const __half* __restrict__ kn16,
    const __half* __restrict__ vn16, const float* __restrict__ sk,
    const float* __restrict__ p, const float* __restrict__ we,
    float* __restrict__ out, _Float16* __restrict__ o16) {
  int lane = threadIdx.x & 63;
  int wv_ = threadIdx.x >> 6;
  int t = blockIdx.x * TPB + wv_;
  int l32 = lane & 31;
  int half_ = lane >> 5;
  int f = 4 * l32;
  int g = l32 & 7;
  int ed = 4 * g;
  int h = l32 >> 3;
  int e0 = offs[t], e1 = offs[t + 1];
  const __half2* qp = (const __half2*)&qn16[t * HC + f];
  float2 q01 = __half22float2(qp[0]), q23 = __half22float2(qp[1]);
  float4 q4 = {q01.x, q01.y, q23.x, q23.y};
  float4 p4 = *(const float4*)&p[t * HC + f];
  const float inv_sqrt = 0.17677669529663687f;
  float m = -1e30f, den = 0.f;
  float4 acc = {0.f, 0.f, 0.f, 0.f}, tac = {0.f, 0.f, 0.f, 0.f};
  for (int base = e0; base < e1; base += 64) {
    int cnt = min(64, e1 - base);
    int li = base + lane;
    int sl = (li < e1) ? srcs[li] : 0;
    int el = (li < e1) ? eids[li] : 0;
    for (int jj = 0; jj < cnt; jj += 2) {
      int j = jj + half_;
      bool val = (j < cnt);
      int jc = min(j, cnt - 1);
      int s = __shfl(sl, jc, 64);
      int eid = __shfl(el, jc, 64);
      const __half2* kp = (const __half2*)&kn16[s * HC + f];
      const __half2* vp = (const __half2*)&vn16[s * HC + f];
      __half2 kh0 = kp[0], kh1 = kp[1];
      __half2 vh0 = vp[0], vh1 = vp[1];
      float4 e4 = *(const float4*)&ea[eid * HID + ed];
      float2 k01 = __half22float2(kh0), k23 = __half22float2(kh1);
      float2 v01 = __half22float2(vh0), v23 = __half22float2(vh1);
      float part = fmaf(q4.x, k01.x, fmaf(q4.y, k01.y,
                   fmaf(q4.z, k23.x, fmaf(q4.w, k23.y,
                   fmaf(p4.x, e4.x, fmaf(p4.y, e4.y,
                   fmaf(p4.z, e4.z, p4.w * e4.w)))))));
      part += __shfl_xor(part, 1, 64);
      part += __shfl_xor(part, 2, 64);
      part += __shfl_xor(part, 4, 64);
      float a = part * inv_sqrt;
      float nm = fmaxf(m, a);
      float sc = __expf(m - nm);
      float w = val ? __expf(a - nm) : 0.f;
      m = nm;
      den = fmaf(den, sc, w);
      acc.x = fmaf(acc.x, sc, w * v01.x);
      acc.y = fmaf(acc.y, sc, w * v01.y);
      acc.z = fmaf(acc.z, sc, w * v23.x);
      acc.w = fmaf(acc.w, sc, w * v23.y);
      tac.x = fmaf(tac.x, sc, w * e4.x);
      tac.y = fmaf(tac.y, sc, w * e4.y);
      tac.z = fmaf(tac.z, sc, w * e4.z);
      tac.w = fmaf(tac.w, sc, w * e4.w);
    }
  }
  float m_o = __shfl_xor(m, 32, 64);
  float M = fmaxf(m, m_o);
  float s_s = __expf(m - M), s_o = __expf(m_o - M);
  float den_o = __shfl_xor(den, 32, 64);
  float dtot = fmaf(den, s_s, den_o * s_o);
  float4 A, T;
  A.x = fmaf(acc.x, s_s, __shfl_xor(acc.x, 32, 64) * s_o);
  A.y = fmaf(acc.y, s_s, __shfl_xor(acc.y, 32, 64) * s_o);
  A.z = fmaf(acc.z, s_s, __shfl_xor(acc.z, 32, 64) * s_o);
  A.w = fmaf(acc.w, s_s, __shfl_xor(acc.w, 32, 64) * s_o);
  T.x = fmaf(tac.x, s_s, __shfl_xor(tac.x, 32, 64) * s_o);
  T.y = fmaf(tac.y, s_s, __shfl_xor(tac.y, 32, 64) * s_o);
  T.z = fmaf(tac.z, s_s, __shfl_xor(tac.z, 32, 64) * s_o);
  T.w = fmaf(tac.w, s_s, __shfl_xor(tac.w, 32, 64) * s_o);
  __shared__ float tl[TPB][4 * 33];
  if (half_ == 0) *(float4*)&tl[wv_][h * 33 + ed] = T;
  float4 fx = {0.f, 0.f, 0.f, 0.f};
  for (int j = 0; j < 32; ++j) {
    float tv = tl[wv_][h * 33 + j];
    float4 w4 = *(const float4*)&we[j * HC + f];
    fx.x = fmaf(tv, w4.x, fx.x);
    fx.y = fmaf(tv, w4.y, fx.y);
    fx.z = fmaf(tv, w4.z, fx.z);
    fx.w = fmaf(tv, w4.w, fx.w);
  }
  float4 sk4 = *(const float4*)&sk[t * HC + f];
  float4 o;
  float rd = (e1 > e0) ? (1.0f / dtot) : 0.f;
  o.x = (A.x + fx.x) * rd + sk4.x;
  o.y = (A.y + fx.y) * rd + sk4.y;
  o.z = (A.z + fx.z) * rd + sk4.z;
  o.w = (A.w + fx.w) * rd + sk4.w;
  o.x = o.x > 0.f ? o.x : __expf(o.x) - 1.f;
  o.y = o.y > 0.f ? o.y : __expf(o.y) - 1.f;
  o.z = o.z > 0.f ? o.z : __expf(o.z) - 1.f;
  o.w = o.w > 0.f ? o.w : __expf(o.w) - 1.f;
  if (half_ == 0) {
    *(float4*)&out[t * HC + f] = o;
    half4v v16 = {(_Float16)o.x, (_Float16)o.y, (_Float16)o.z, (_Float16)o.w};
    *(half4v*)&o16[t * HC + f] = v16;
  }
}

// ---------------- global mean pool ----------------
__global__ __launch_bounds__(128) void k_pool_sum(const float* __restrict__ h,
                                                  const int* __restrict__ batch,
                                                  float* __restrict__ psum) {
  int c = threadIdx.x;
  int n0 = blockIdx.x * PNB;
  int n1 = n0 + PNB;
  float acc = 0.f;
  int curb = batch[n0];
  for (int n = n0; n < n1; ++n) {
    int b = batch[n];
    if (b != curb) {
      atomicAdd(&psum[curb * HC + c], acc);
      acc = 0.f;
      curb = b;
    }
    acc += h[n * HC + c];
  }
  atomicAdd(&psum[curb * HC + c], acc);
}

// ---------------- classifier + log_softmax ----------------
__global__ __launch_bounds__(1024) void k_classify(const float* __restrict__ psum,
                                                   const int* __restrict__ batch,
                                                   const float* __restrict__ wlin,
                                                   const float* __restrict__ blin,
                                                   float* __restrict__ out) {
  int tid = threadIdx.x;
  int b = tid >> 4, o = tid & 15;
  int lo = 0, hi = N_NODES;
  while (lo < hi) { int mid = (lo + hi) >> 1; if (batch[mid] < b) lo = mid + 1; else hi = mid; }
  int start = lo;
  lo = 0; hi = N_NODES;
  while (lo < hi) { int mid = (lo + hi) >> 1; if (batch[mid] <= b) lo = mid + 1; else hi = mid; }
  float cnt = fmaxf((float)(lo - start), 1.0f);
  float dot = 0.f;
  for (int d = 0; d < HC; ++d) dot = fmaf(psum[b * HC + d], wlin[d * OUT_C + o], dot);
  float acc = dot / cnt + blin[o];
  float mx = acc;
#pragma unroll
  for (int off = 8; off > 0; off >>= 1) mx = fmaxf(mx, __shfl_xor(mx, off, 64));
  float ex = __expf(acc - mx);
  float sum = ex;
#pragma unroll
  for (int off = 8; off > 0; off >>= 1) sum += __shfl_xor(sum, off, 64);
  out[tid] = acc - mx - logf(sum);
}

extern "C" void kernel_launch(void* const* d_in, const int* in_sizes, int n_in,
                              void* d_out, int out_size, void* d_ws, size_t ws_size,
                              hipStream_t stream) {
  const float* x = (const float*)d_in[0];
  const int* ei = (const int*)d_in[1];
  const float* ea = (const float*)d_in[2];
  const int* batch = (const int*)d_in[3];
  const float* wq1 = (const float*)d_in[4];  const float* bq1 = (const float*)d_in[5];
  const float* wk1 = (const float*)d_in[6];  const float* bk1 = (const float*)d_in[7];
  const float* wv1 = (const float*)d_in[8];  const float* bv1 = (const float*)d_in[9];
  const float* we1 = (const float*)d_in[10];
  const float* ws1 = (const float*)d_in[11]; const float* bs1 = (const float*)d_in[12];
  const float* wq2 = (const float*)d_in[13]; const float* bq2 = (const float*)d_in[14];
  const float* wk2 = (const float*)d_in[15]; const float* bk2 = (const float*)d_in[16];
  const float* wv2 = (const float*)d_in[17]; const float* bv2 = (const float*)d_in[18];
  const float* we2 = (const float*)d_in[19];
  const float* ws2 = (const float*)d_in[20]; const float* bs2 = (const float*)d_in[21];
  const float* wlin = (const float*)d_in[22]; const float* blin = (const float*)d_in[23];

  const int* srcI = ei;
  const int* tgtI = ei + N_EDGES;

  char* wsb = (char*)d_ws;
  size_t off = 0;
  auto alloc = [&](size_t bytes) -> void* {
    void* ptr = wsb + off;
    off += (bytes + 255) & ~(size_t)255;
    return ptr;
  };
  __half* qn16 = (__half*)alloc((size_t)N_NODES * HC * 2);
  __half* kn16 = (__half*)alloc((size_t)N_NODES * HC * 2);
  __half* vn16 = (__half*)alloc((size_t)N_NODES * HC * 2);
  float* sk = (float*)alloc((size_t)N_NODES * HC * 4);
  float* p  = (float*)alloc((size_t)N_NODES * HC * 4);
  float* h  = (float*)alloc((size_t)N_NODES * HC * 4);
  _Float16* in16 = (_Float16*)alloc((size_t)N_NODES * HC * 2);  // x16, then h16
  _Float16* wt1 = (_Float16*)alloc((size_t)512 * HC * 2);
  _Float16* wt2 = (_Float16*)alloc((size_t)512 * HC * 2);
  float* psum = (float*)alloc((size_t)NGRAPH * HC * 4);
  int* deg    = (int*)alloc((size_t)N_NODES * 4);
  int* offs   = (int*)alloc((size_t)(N_NODES + 1) * 4);
  int* cursor = (int*)alloc((size_t)N_NODES * 4);
  int* srcs   = (int*)alloc((size_t)N_EDGES * 4);
  int* eids   = (int*)alloc((size_t)N_EDGES * 4);

  // CSR build
  hipMemsetAsync(deg, 0, (size_t)N_NODES * 4, stream);
  k_hist<<<(N_EDGES + 255) / 256, 256, 0, stream>>>(tgtI, deg);
  k_scan<<<1, 1024, 0, stream>>>(deg, offs, cursor);
  k_scatter<<<(N_EDGES + 255) / 256, 256, 0, stream>>>(srcI, tgtI, cursor, srcs, eids);

  // Conversions
  k_conv_x<<<(N_NODES * HC + 255) / 256, 256, 0, stream>>>(x, in16);
  k_conv_w<<<512, 128, 0, stream>>>(wq1, wk1, wv1, ws1, wt1);
  k_conv_w<<<512, 128, 0, stream>>>(wq2, wk2, wv2, ws2, wt2);

  dim3 gemm_grid((N_NODES + 63) / 64, 4);
  // Layer 1
  k_gemm<<<gemm_grid, 256, 0, stream>>>(in16, wt1, bq1, bk1, bv1, bs1,
                                        qn16, kn16, vn16, sk);
  k_pcomp<<<N_NODES / 16, 128, 0, stream>>>(qn16, we1, p);
  k_edge_attn<<<N_NODES / TPB, 64 * TPB, 0, stream>>>(offs, srcs, eids, ea, qn16,
                                                      kn16, vn16, sk, p, we1, h, in16);
  // Layer 2
  k_gemm<<<gemm_grid, 256, 0, stream>>>(in16, wt2, bq2, bk2, bv2, bs2,
                                        qn16, kn16, vn16, sk);
  k_pcomp<<<N_NODES / 16, 128, 0, stream>>>(qn16, we2, p);
  k_edge_attn<<<N_NODES / TPB, 64 * TPB, 0, stream>>>(offs, srcs, eids, ea, qn16,
                                                      kn16, vn16, sk, p, we2, h, in16);

  // Pool + classify
  hipMemsetAsync(psum, 0, (size_t)NGRAPH * HC * 4, stream);
  k_pool_sum<<<N_NODES / PNB, 128, 0, stream>>>(h, batch, psum);
  k_classify<<<1, 1024, 0, stream>>>(psum, batch, wlin, blin, (float*)d_out);
}